// Round 1
// baseline (554.381 us; speedup 1.0000x reference)
//
#include <hip/hip_runtime.h>
#include <hip/hip_bf16.h>

// Problem constants
#define B_N 16384
#define A_N 32
#define U_N 64
#define S_N 2048
#define E_N 32
#define HYP_N 64
#define H_N 4
#define NPAD 320    // padded GEMM N (288 real cols + 32 zero)
#define NREAL 288   // 256 selector-hypernet cols + 32 v-net cols

// workspace layout (in floats)
#define WS_WPAD 0
#define WS_C1   (S_N * NPAD)                 // 655360
#define WS_PMAG (WS_C1 + B_N * NREAL)        // 5373952
#define WS_PENT (WS_PMAG + B_N)              // 5390336
// total floats = WS_PENT + H_N*B_N = 5455872  (~21.8 MB)

// output layout (floats): head_attend [B,A] | v [B] | mag scalar | ent [H]
#define OUT_V   (B_N * A_N)     // 524288
#define OUT_MAG (OUT_V + B_N)   // 540672
#define OUT_ENT (OUT_MAG + 1)   // 540673

// ---------------------------------------------------------------------------
// Pack [sel_w1 (H,S,HYP) | v_w1 (S,E)] into Wpad[S][320], zero-padded cols.
// Column j<256: head h=j>>6, k=j&63 -> sel_w1[h][s][k]. 256<=j<288: v_w1[s][j-256].
// ---------------------------------------------------------------------------
__global__ void pack_w_kernel(const float* __restrict__ sel_w1,
                              const float* __restrict__ v_w1,
                              float* __restrict__ Wpad) {
    int idx = blockIdx.x * 256 + threadIdx.x;
    if (idx >= S_N * NPAD) return;
    int s = idx / NPAD;
    int j = idx - s * NPAD;
    float val = 0.0f;
    if (j < 256) {
        int h = j >> 6, k = j & 63;
        val = sel_w1[(size_t)(h * S_N + s) * HYP_N + k];
    } else if (j < NREAL) {
        val = v_w1[(size_t)s * E_N + (j - 256)];
    }
    Wpad[idx] = val;
}

// ---------------------------------------------------------------------------
// GEMM1: C1[B][288] = relu(states[B][2048] @ Wpad[2048][320] + bias)
// BM=64 BN=64 BK=32, 256 threads, 4x4 register tile per thread.
// bias: col<256 -> sel_b1[col], 256..287 -> v_b1[col-256].
// ---------------------------------------------------------------------------
#define BM 64
#define BN 64
#define BK 32

__global__ __launch_bounds__(256) void gemm1_kernel(
        const float* __restrict__ states, const float* __restrict__ Wpad,
        const float* __restrict__ sel_b1, const float* __restrict__ v_b1,
        float* __restrict__ C1) {
    __shared__ float As[BK][BM + 4];   // stride 68: keeps float4 alignment
    __shared__ float Bs[BK][BN];
    const int t  = threadIdx.x;
    const int m0 = blockIdx.x * BM;
    const int n0 = blockIdx.y * BN;
    const int tx = t & 15;     // 16 col-groups of 4
    const int ty = t >> 4;     // 16 row-groups of 4

    float acc[4][4];
#pragma unroll
    for (int i = 0; i < 4; ++i)
#pragma unroll
        for (int j = 0; j < 4; ++j) acc[i][j] = 0.0f;

    for (int k0 = 0; k0 < S_N; k0 += BK) {
#pragma unroll
        for (int l = 0; l < 2; ++l) {
            int f = t + l * 256;                 // 512 float4 per tile
            // A tile: 64 rows x 32 k
            int ar = f >> 3, akq = (f & 7) << 2;
            float4 av = *(const float4*)(states + (size_t)(m0 + ar) * S_N + k0 + akq);
            As[akq + 0][ar] = av.x; As[akq + 1][ar] = av.y;
            As[akq + 2][ar] = av.z; As[akq + 3][ar] = av.w;
            // B tile: 32 k x 64 n
            int bkr = f >> 4, bnc = (f & 15) << 2;
            float4 bv = *(const float4*)(Wpad + (size_t)(k0 + bkr) * NPAD + n0 + bnc);
            *(float4*)&Bs[bkr][bnc] = bv;
        }
        __syncthreads();
#pragma unroll
        for (int k = 0; k < BK; ++k) {
            float4 a4 = *(const float4*)&As[k][ty * 4];
            float4 b4 = *(const float4*)&Bs[k][tx * 4];
            float ar[4] = {a4.x, a4.y, a4.z, a4.w};
            float br[4] = {b4.x, b4.y, b4.z, b4.w};
#pragma unroll
            for (int i = 0; i < 4; ++i)
#pragma unroll
                for (int j = 0; j < 4; ++j)
                    acc[i][j] = fmaf(ar[i], br[j], acc[i][j]);
        }
        __syncthreads();
    }

    int ncol = n0 + tx * 4;
    if (ncol < NREAL) {   // n multiple of 4, so ncol+3 < 288 too
#pragma unroll
        for (int i = 0; i < 4; ++i) {
            int m = m0 + ty * 4 + i;
            float4 o;
            float* oo = &o.x;
#pragma unroll
            for (int j = 0; j < 4; ++j) {
                int n = ncol + j;
                float bias = (n < 256) ? sel_b1[n] : v_b1[n - 256];
                float v = acc[i][j] + bias;
                oo[j] = v > 0.0f ? v : 0.0f;
            }
            *(float4*)(C1 + (size_t)m * NREAL + ncol) = o;
        }
    }
}

// ---------------------------------------------------------------------------
// Epilogue: one block (128 thr) per batch row.
//   selectors[h][e] = sum_k h1[h][k] * sel_w2[h][k][e]
//   t[h][u]        = sum_e selectors[h][e] * key_w[h][u][e]
//   logits[h][a]   = sum_u us[a][u] * t[h][u]        (keys never materialized)
//   softmax over a; head_attend = sum_h w; v; partial mag/entropy sums.
// ---------------------------------------------------------------------------
__global__ __launch_bounds__(128) void epilogue_kernel(
        const float* __restrict__ states, const float* __restrict__ C1,
        const float* __restrict__ sel_w2, const float* __restrict__ key_w,
        const float* __restrict__ v_w2, const float* __restrict__ v_b2,
        float* __restrict__ out, float* __restrict__ part_mag,
        float* __restrict__ part_ent) {
    __shared__ float us[A_N * 65];       // stride 65 -> bank (a+u)%32, conflict-free
    __shared__ float h1s[NREAL];
    __shared__ float sel_s[H_N * E_N];   // 128
    __shared__ float t_s[H_N * U_N];     // 256
    __shared__ float w_s[H_N * A_N];     // 128
    __shared__ float red_s[2];

    const int b = blockIdx.x;
    const int t = threadIdx.x;

    // stage states row: coalesced float4 global reads, scatter to stride-65 LDS
    {
        const float4* src = (const float4*)(states + (size_t)b * S_N);
#pragma unroll
        for (int i = 0; i < 4; ++i) {
            int f = t + i * 128;          // float4 index 0..511
            float4 v4 = src[f];
            int a = f >> 4, u = (f & 15) << 2;
            float* dst = &us[a * 65 + u];
            dst[0] = v4.x; dst[1] = v4.y; dst[2] = v4.z; dst[3] = v4.w;
        }
    }
    for (int i = t; i < NREAL; i += 128) h1s[i] = C1[(size_t)b * NREAL + i];
    __syncthreads();

    // v head: dot(relu'd v columns, v_w2) + v_b2
    if (t < 32) {
        float p = h1s[256 + t] * v_w2[t];
#pragma unroll
        for (int o = 16; o > 0; o >>= 1) p += __shfl_down(p, o, 32);
        if (t == 0) out[OUT_V + b] = p + v_b2[0];
    }

    // selectors: thread t -> (h = t>>5, e = t&31)
    {
        int h = t >> 5, e = t & 31;
        const float* w2 = sel_w2 + (size_t)(h * HYP_N) * E_N + e;
        const float* hh = h1s + h * HYP_N;
        float s = 0.0f;
#pragma unroll
        for (int k = 0; k < HYP_N; ++k) s = fmaf(hh[k], w2[k * E_N], s);
        sel_s[t] = s;
    }
    __syncthreads();

    // t[h][u] = key_w[h] @ selectors[h]
#pragma unroll
    for (int l = 0; l < 2; ++l) {
        int idx = t + l * 128;
        int h = idx >> 6, u = idx & 63;
        const float* kw = key_w + (size_t)(h * U_N + u) * E_N;
        const float* sh = sel_s + h * E_N;
        float s = 0.0f;
#pragma unroll
        for (int e = 0; e < E_N; ++e) s = fmaf(sh[e], kw[e], s);
        t_s[idx] = s;
    }
    __syncthreads();

    // logits + softmax: thread t -> (h = t>>5, a = t&31); a-groups align to
    // 32-lane shuffle segments.
    const int h = t >> 5, a = t & 31;
    float l = 0.0f;
    {
        const float* ua = us + a * 65;
        const float* th = t_s + h * U_N;
#pragma unroll
        for (int u = 0; u < U_N; ++u) l = fmaf(ua[u], th[u], l);
    }
    float mag = l * l;

    float x = l * 0.17677669529663687f;   // 1/sqrt(E=32)
    float m = x;
#pragma unroll
    for (int o = 16; o > 0; o >>= 1) m = fmaxf(m, __shfl_xor(m, o, 32));
    float p = expf(x - m);
    float denom = p;
#pragma unroll
    for (int o = 16; o > 0; o >>= 1) denom += __shfl_xor(denom, o, 32);
    float w = p / denom;

    float ent = w * logf(w + 1e-8f);
    float entsum = ent;
#pragma unroll
    for (int o = 16; o > 0; o >>= 1) entsum += __shfl_xor(entsum, o, 32);
    if (a == 0) part_ent[(size_t)h * B_N + b] = entsum;

    w_s[t] = w;
    // block mag reduction: full-wave xor then 2-way LDS combine
#pragma unroll
    for (int o = 32; o > 0; o >>= 1) mag += __shfl_xor(mag, o, 64);
    if ((t & 63) == 0) red_s[t >> 6] = mag;
    __syncthreads();

    if (t < 32) {
        out[(size_t)b * A_N + t] = w_s[t] + w_s[32 + t] + w_s[64 + t] + w_s[96 + t];
    }
    if (t == 0) part_mag[b] = red_s[0] + red_s[1];
}

// ---------------------------------------------------------------------------
// Deterministic final reduction: block 0 -> mag scalar, blocks 1..4 -> ent[h]
// ---------------------------------------------------------------------------
__global__ __launch_bounds__(256) void finalize_kernel(
        const float* __restrict__ part_mag, const float* __restrict__ part_ent,
        float* __restrict__ out) {
    int which = blockIdx.x;   // 0..4
    const float* src = (which == 0) ? part_mag : (part_ent + (size_t)(which - 1) * B_N);
    float s = 0.0f;
    for (int i = threadIdx.x; i < B_N; i += 256) s += src[i];
#pragma unroll
    for (int o = 32; o > 0; o >>= 1) s += __shfl_xor(s, o, 64);
    __shared__ float red[4];
    if ((threadIdx.x & 63) == 0) red[threadIdx.x >> 6] = s;
    __syncthreads();
    if (threadIdx.x == 0) {
        float tot = red[0] + red[1] + red[2] + red[3];
        if (which == 0) out[OUT_MAG] = 1e-3f * tot / (float)(B_N * A_N);
        else out[OUT_ENT + which - 1] = -tot / (float)B_N;
    }
}

// ---------------------------------------------------------------------------
extern "C" void kernel_launch(void* const* d_in, const int* in_sizes, int n_in,
                              void* d_out, int out_size, void* d_ws, size_t ws_size,
                              hipStream_t stream) {
    const float* states = (const float*)d_in[1];
    const float* sel_w1 = (const float*)d_in[2];
    const float* sel_b1 = (const float*)d_in[3];
    const float* sel_w2 = (const float*)d_in[4];
    const float* key_w  = (const float*)d_in[5];
    const float* v_w1   = (const float*)d_in[6];
    const float* v_b1   = (const float*)d_in[7];
    const float* v_w2   = (const float*)d_in[8];
    const float* v_b2   = (const float*)d_in[9];
    float* out = (float*)d_out;
    float* ws  = (float*)d_ws;

    float* Wpad = ws + WS_WPAD;
    float* C1   = ws + WS_C1;
    float* pmag = ws + WS_PMAG;
    float* pent = ws + WS_PENT;

    pack_w_kernel<<<dim3((S_N * NPAD + 255) / 256), dim3(256), 0, stream>>>(
        sel_w1, v_w1, Wpad);
    gemm1_kernel<<<dim3(B_N / BM, NPAD / BN), dim3(256), 0, stream>>>(
        states, Wpad, sel_b1, v_b1, C1);
    epilogue_kernel<<<dim3(B_N), dim3(128), 0, stream>>>(
        states, C1, sel_w2, key_w, v_w2, v_b2, out, pmag, pent);
    finalize_kernel<<<dim3(5), dim3(256), 0, stream>>>(pmag, pent, out);
}

// Round 2
// 340.643 us; speedup vs baseline: 1.6275x; 1.6275x over previous
//
#include <hip/hip_runtime.h>
#include <hip/hip_bf16.h>

// Problem constants
#define B_N 16384
#define A_N 32
#define U_N 64
#define S_N 2048
#define E_N 32
#define HYP_N 64
#define H_N 4
#define NPAD 320    // padded GEMM N (288 real + 32 zero)
#define NREAL 288   // 256 selector-hypernet cols + 32 v-net cols

// workspace byte offsets (all 16B-aligned)
#define WS_SB    0                        // states bf16: 33554432*2 = 67108864
#define WS_WT    67108864                 // Wt bf16 [NPAD][S]: 655360*2
#define WS_C1    (67108864 + 1310720)     // C1 bf16 [B][288]: 9437184
#define WS_KWT   (WS_C1 + 9437184)        // key_wT fp32 [H][E][U]: 32768
#define WS_PMAG  (WS_KWT + 32768)         // 65536
#define WS_PENT  (WS_PMAG + 65536)        // 262144
// total ~78.2 MB

// output layout (floats): head_attend [B,A] | v [B] | mag | ent [H]
#define OUT_V   (B_N * A_N)
#define OUT_MAG (OUT_V + B_N)
#define OUT_ENT (OUT_MAG + 1)

typedef __attribute__((ext_vector_type(8))) short bf16x8_t;
typedef __attribute__((ext_vector_type(4))) float floatx4_t;

#define AS1(p) ((const __attribute__((address_space(1))) void*)(p))
#define AS3(p) ((__attribute__((address_space(3))) void*)(p))

__device__ __forceinline__ unsigned short f2b(float f) {
    union { float f; unsigned u; } v; v.f = f;
    unsigned r = v.u + 0x7FFFu + ((v.u >> 16) & 1u);   // RNE
    return (unsigned short)(r >> 16);
}
__device__ __forceinline__ float b2f(unsigned x) {
    union { unsigned u; float f; } v; v.u = x << 16; return v.f;
}

// ---------------------------------------------------------------------------
// states fp32 -> bf16 (8 elems/thread)
// ---------------------------------------------------------------------------
__global__ __launch_bounds__(256) void cvt_states_kernel(
        const float* __restrict__ in, unsigned short* __restrict__ outp) {
    size_t i = ((size_t)blockIdx.x * 256 + threadIdx.x) * 8;
    float4 a = *(const float4*)(in + i);
    float4 b = *(const float4*)(in + i + 4);
    uint4 o;
    o.x = (unsigned)f2b(a.x) | ((unsigned)f2b(a.y) << 16);
    o.y = (unsigned)f2b(a.z) | ((unsigned)f2b(a.w) << 16);
    o.z = (unsigned)f2b(b.x) | ((unsigned)f2b(b.y) << 16);
    o.w = (unsigned)f2b(b.z) | ((unsigned)f2b(b.w) << 16);
    *(uint4*)(outp + i) = o;
}

// ---------------------------------------------------------------------------
// Pack: Wt bf16 [NPAD][S] (= W^T of [sel_w1 | v_w1 | 0]) and key_wT [H][E][U]
// ---------------------------------------------------------------------------
__global__ __launch_bounds__(256) void pack_w_kernel(
        const float* __restrict__ sel_w1, const float* __restrict__ v_w1,
        const float* __restrict__ key_w,
        unsigned short* __restrict__ Wt, float* __restrict__ kwT) {
    int idx = blockIdx.x * 256 + threadIdx.x;
    if (idx < NPAD * S_N) {
        int n = idx >> 11;          // / 2048
        int k = idx & 2047;
        float val = 0.0f;
        if (n < 256) {
            int h = n >> 6, kk = n & 63;
            val = sel_w1[((size_t)h * S_N + k) * HYP_N + kk];
        } else if (n < NREAL) {
            val = v_w1[(size_t)k * E_N + (n - 256)];
        }
        Wt[idx] = f2b(val);
    } else if (idx < NPAD * S_N + H_N * E_N * U_N) {
        int j = idx - NPAD * S_N;          // [h][e][u]
        int h = j >> 11, e = (j >> 6) & 31, u = j & 63;
        kwT[j] = key_w[((size_t)h * U_N + u) * E_N + e];
    }
}

// ---------------------------------------------------------------------------
// MFMA GEMM: C1[B][288] = relu_bf16(states_bf16 @ W + bias)
// BM=128 BN=64 BK=64, 256 thr (4 waves, 2x2), 16x16x32 bf16 MFMA,
// global_load_lds width=16 staging, XOR-swizzled 16B chunks.
// ---------------------------------------------------------------------------
#define GM_BM 128
#define GM_BN 64
#define GM_BK 64

__global__ __launch_bounds__(256) void gemm1_mfma_kernel(
        const unsigned short* __restrict__ Sb, const unsigned short* __restrict__ Wt,
        const float* __restrict__ sel_b1, const float* __restrict__ v_b1,
        unsigned short* __restrict__ C1) {
    __shared__ __align__(16) unsigned short Asm[GM_BM * GM_BK];  // [r][k] 16KB
    __shared__ __align__(16) unsigned short Bsm[GM_BN * GM_BK];  // [n][k]  8KB

    const int t = threadIdx.x;
    const int lane = t & 63;
    const int w = t >> 6;
    const int m0 = blockIdx.y * GM_BM;
    const int n0 = blockIdx.x * GM_BN;
    const int mw = (w >> 1) * 64;
    const int nw = (w & 1) * 32;

    floatx4_t acc[4][2] = {};

    for (int k0 = 0; k0 < S_N; k0 += GM_BK) {
        __syncthreads();   // previous tile's ds_reads done before overwrite
#pragma unroll
        for (int i = 0; i < 4; ++i) {       // A: 1024 16B chunks
            int p = i * 256 + t;
            int r = p >> 3;
            int cl = (p & 7) ^ (r & 7);
            const unsigned short* g = Sb + (size_t)(m0 + r) * S_N + k0 + cl * 8;
            __builtin_amdgcn_global_load_lds(AS1(g), AS3(Asm + p * 8), 16, 0, 0);
        }
#pragma unroll
        for (int i = 0; i < 2; ++i) {       // B: 512 16B chunks
            int p = i * 256 + t;
            int n = p >> 3;
            int cl = (p & 7) ^ (n & 7);
            const unsigned short* g = Wt + (size_t)(n0 + n) * S_N + k0 + cl * 8;
            __builtin_amdgcn_global_load_lds(AS1(g), AS3(Bsm + p * 8), 16, 0, 0);
        }
        __syncthreads();   // drain staging

#pragma unroll
        for (int s = 0; s < 2; ++s) {       // two K=32 steps
            const int c = s * 4 + (lane >> 4);
            bf16x8_t bfr[2];
#pragma unroll
            for (int nt = 0; nt < 2; ++nt) {
                int n = nw + nt * 16 + (lane & 15);
                int ph = c ^ (n & 7);
                bfr[nt] = *(const bf16x8_t*)(Bsm + n * 64 + ph * 8);
            }
#pragma unroll
            for (int mt = 0; mt < 4; ++mt) {
                int r = mw + mt * 16 + (lane & 15);
                int ph = c ^ (r & 7);
                bf16x8_t afr = *(const bf16x8_t*)(Asm + r * 64 + ph * 8);
#pragma unroll
                for (int nt = 0; nt < 2; ++nt)
                    acc[mt][nt] = __builtin_amdgcn_mfma_f32_16x16x32_bf16(
                        afr, bfr[nt], acc[mt][nt], 0, 0, 0);
            }
        }
    }

    // bias + relu, store bf16. C/D layout: col=lane&15, row=(lane>>4)*4+reg
#pragma unroll
    for (int nt = 0; nt < 2; ++nt) {
        int n = n0 + nw + nt * 16 + (lane & 15);
        if (n >= NREAL) continue;
        float bias = (n < 256) ? sel_b1[n] : v_b1[n - 256];
#pragma unroll
        for (int mt = 0; mt < 4; ++mt) {
            int rbase = m0 + mw + mt * 16 + (lane >> 4) * 4;
#pragma unroll
            for (int rg = 0; rg < 4; ++rg) {
                float v = acc[mt][nt][rg] + bias;
                C1[(size_t)(rbase + rg) * NREAL + n] = f2b(v > 0.0f ? v : 0.0f);
            }
        }
    }
}

// ---------------------------------------------------------------------------
// Epilogue v2: 256 thr = 4 waves, one wave per batch row.
// ---------------------------------------------------------------------------
__global__ __launch_bounds__(256) void epilogue2_kernel(
        const unsigned short* __restrict__ Sb, const unsigned short* __restrict__ C1,
        const float* __restrict__ sel_w2, const float* __restrict__ kwT,
        const float* __restrict__ v_w2, const float* __restrict__ v_b2,
        float* __restrict__ out, float* __restrict__ pmag, float* __restrict__ pent) {
    __shared__ float us[4][A_N * 65];    // stride 65: logits phase conflict-free
    __shared__ float h1s[4][NREAL];
    __shared__ float sel_s[4][H_N * E_N];
    __shared__ float ts[4][H_N * U_N];

    const int t = threadIdx.x;
    const int w = t >> 6;
    const int lane = t & 63;
    const int b = blockIdx.x * 4 + w;

    // stage states row (bf16 -> fp32 LDS)
#pragma unroll
    for (int i = 0; i < 4; ++i) {
        int c = i * 64 + lane;                       // 16B chunk 0..255
        uint4 v = *(const uint4*)(Sb + (size_t)b * S_N + c * 8);
        int a = c >> 3, u0 = (c & 7) * 8;
        float* d = &us[w][a * 65 + u0];
        d[0] = b2f(v.x & 0xffff); d[1] = b2f(v.x >> 16);
        d[2] = b2f(v.y & 0xffff); d[3] = b2f(v.y >> 16);
        d[4] = b2f(v.z & 0xffff); d[5] = b2f(v.z >> 16);
        d[6] = b2f(v.w & 0xffff); d[7] = b2f(v.w >> 16);
    }
    // stage h1 row (288 bf16 = 36 chunks)
    if (lane < 36) {
        uint4 v = *(const uint4*)(C1 + (size_t)b * NREAL + lane * 8);
        float* d = &h1s[w][lane * 8];
        d[0] = b2f(v.x & 0xffff); d[1] = b2f(v.x >> 16);
        d[2] = b2f(v.y & 0xffff); d[3] = b2f(v.y >> 16);
        d[4] = b2f(v.z & 0xffff); d[5] = b2f(v.z >> 16);
        d[6] = b2f(v.w & 0xffff); d[7] = b2f(v.w >> 16);
    }
    __syncthreads();

    // selectors[h][e]
#pragma unroll
    for (int l = 0; l < 2; ++l) {
        int idx = l * 64 + lane, h = idx >> 5, e = idx & 31;
        const float* hh = &h1s[w][h * HYP_N];
        const float* w2 = sel_w2 + (size_t)h * HYP_N * E_N + e;
        float s = 0.0f;
#pragma unroll
        for (int k = 0; k < HYP_N; ++k) s = fmaf(hh[k], w2[(size_t)k * E_N], s);
        sel_s[w][idx] = s;
    }
    __syncthreads();

    // t[h][u] via key_wT (coalesced over u)
#pragma unroll
    for (int l = 0; l < 4; ++l) {
        int idx = l * 64 + lane, h = idx >> 6, u = idx & 63;
        const float* sh = &sel_s[w][h * E_N];
        const float* kw = kwT + (size_t)h * E_N * U_N + u;
        float s = 0.0f;
#pragma unroll
        for (int e = 0; e < E_N; ++e) s = fmaf(sh[e], kw[(size_t)e * U_N], s);
        ts[w][idx] = s;
    }
    __syncthreads();

    // logits + softmax (32-lane segments align with (h,a) groups)
    float wgt[2];
    float mag = 0.0f;
#pragma unroll
    for (int l = 0; l < 2; ++l) {
        int idx = l * 64 + lane, h = idx >> 5, a = idx & 31;
        const float* ua = &us[w][a * 65];
        const float* th = &ts[w][h * U_N];
        float lg = 0.0f;
#pragma unroll
        for (int u = 0; u < U_N; ++u) lg = fmaf(ua[u], th[u], lg);
        mag += lg * lg;

        float x = lg * 0.17677669529663687f;  // 1/sqrt(32)
        float m = x;
#pragma unroll
        for (int o = 16; o > 0; o >>= 1) m = fmaxf(m, __shfl_xor(m, o, 32));
        float p = expf(x - m);
        float den = p;
#pragma unroll
        for (int o = 16; o > 0; o >>= 1) den += __shfl_xor(den, o, 32);
        float wv = p / den;
        wgt[l] = wv;

        float ent = wv * logf(wv + 1e-8f);
#pragma unroll
        for (int o = 16; o > 0; o >>= 1) ent += __shfl_xor(ent, o, 32);
        if (a == 0) pent[(size_t)h * B_N + b] = ent;
    }

    // mag: 64-lane reduce (covers all 128 logits of the row)
#pragma unroll
    for (int o = 32; o > 0; o >>= 1) mag += __shfl_xor(mag, o, 64);
    if (lane == 0) pmag[b] = mag;

    // head_attend: lane has (h, h+2) for a=lane&31; partner lane^32 has (h^1, (h^1)+2)
    float partial = wgt[0] + wgt[1];
    partial += __shfl_xor(partial, 32, 64);
    if (lane < 32) out[(size_t)b * A_N + lane] = partial;

    // v head
    if (lane < 32) {
        float p = h1s[w][256 + lane] * v_w2[lane];
#pragma unroll
        for (int o = 16; o > 0; o >>= 1) p += __shfl_xor(p, o, 32);
        if (lane == 0) out[OUT_V + b] = p + v_b2[0];
    }
}

// ---------------------------------------------------------------------------
// Deterministic final reduction
// ---------------------------------------------------------------------------
__global__ __launch_bounds__(256) void finalize_kernel(
        const float* __restrict__ pmag, const float* __restrict__ pent,
        float* __restrict__ out) {
    int which = blockIdx.x;   // 0..4
    const float* src = (which == 0) ? pmag : (pent + (size_t)(which - 1) * B_N);
    float s = 0.0f;
    for (int i = threadIdx.x; i < B_N; i += 256) s += src[i];
#pragma unroll
    for (int o = 32; o > 0; o >>= 1) s += __shfl_xor(s, o, 64);
    __shared__ float red[4];
    if ((threadIdx.x & 63) == 0) red[threadIdx.x >> 6] = s;
    __syncthreads();
    if (threadIdx.x == 0) {
        float tot = red[0] + red[1] + red[2] + red[3];
        if (which == 0) out[OUT_MAG] = 1e-3f * tot / (float)(B_N * A_N);
        else out[OUT_ENT + which - 1] = -tot / (float)B_N;
    }
}

// ---------------------------------------------------------------------------
extern "C" void kernel_launch(void* const* d_in, const int* in_sizes, int n_in,
                              void* d_out, int out_size, void* d_ws, size_t ws_size,
                              hipStream_t stream) {
    const float* states = (const float*)d_in[1];
    const float* sel_w1 = (const float*)d_in[2];
    const float* sel_b1 = (const float*)d_in[3];
    const float* sel_w2 = (const float*)d_in[4];
    const float* key_w  = (const float*)d_in[5];
    const float* v_w1   = (const float*)d_in[6];
    const float* v_b1   = (const float*)d_in[7];
    const float* v_w2   = (const float*)d_in[8];
    const float* v_b2   = (const float*)d_in[9];
    float* out = (float*)d_out;
    char* wsb  = (char*)d_ws;

    unsigned short* Sb  = (unsigned short*)(wsb + WS_SB);
    unsigned short* Wt  = (unsigned short*)(wsb + WS_WT);
    unsigned short* C1  = (unsigned short*)(wsb + WS_C1);
    float* kwT          = (float*)(wsb + WS_KWT);
    float* pmag         = (float*)(wsb + WS_PMAG);
    float* pent         = (float*)(wsb + WS_PENT);

    cvt_states_kernel<<<dim3(B_N * S_N / (256 * 8)), dim3(256), 0, stream>>>(states, Sb);
    pack_w_kernel<<<dim3((NPAD * S_N + H_N * E_N * U_N + 255) / 256), dim3(256), 0, stream>>>(
        sel_w1, v_w1, key_w, Wt, kwT);
    gemm1_mfma_kernel<<<dim3(NPAD / GM_BN, B_N / GM_BM), dim3(256), 0, stream>>>(
        Sb, Wt, sel_b1, v_b1, C1);
    epilogue2_kernel<<<dim3(B_N / 4), dim3(256), 0, stream>>>(
        Sb, C1, sel_w2, kwT, v_w2, v_b2, out, pmag, pent);
    finalize_kernel<<<dim3(5), dim3(256), 0, stream>>>(pmag, pent, out);
}

// Round 3
// 318.870 us; speedup vs baseline: 1.7386x; 1.0683x over previous
//
#include <hip/hip_runtime.h>
#include <hip/hip_bf16.h>

// Problem constants
#define B_N 16384
#define A_N 32
#define U_N 64
#define S_N 2048
#define E_N 32
#define HYP_N 64
#define H_N 4
#define NREAL 288   // 256 selector-hypernet cols + 32 v-net cols

// workspace byte offsets (all 16B-aligned)
#define WS_WT    0                         // Wt bf16 [NREAL][S]: 1179648 B
#define WS_C1    1179648                   // C1 bf16 [B][288]: 9437184 B
#define WS_KWT   (WS_C1 + 9437184)         // key_wT fp32 [H][E][U]: 32768 B
#define WS_PMAG  (WS_KWT + 32768)
#define WS_PENT  (WS_PMAG + 65536)
// total ~11 MB

// output layout (floats): head_attend [B,A] | v [B] | mag | ent [H]
#define OUT_V   (B_N * A_N)
#define OUT_MAG (OUT_V + B_N)
#define OUT_ENT (OUT_MAG + 1)

typedef __attribute__((ext_vector_type(8))) short bf16x8_t;
typedef __attribute__((ext_vector_type(4))) float floatx4_t;

#define AS1(p) ((const __attribute__((address_space(1))) void*)(p))
#define AS3(p) ((__attribute__((address_space(3))) void*)(p))

__device__ __forceinline__ unsigned short f2b(float f) {
    union { float f; unsigned u; } v; v.f = f;
    unsigned r = v.u + 0x7FFFu + ((v.u >> 16) & 1u);   // RNE
    return (unsigned short)(r >> 16);
}
__device__ __forceinline__ float b2f(unsigned x) {
    union { unsigned u; float f; } v; v.u = x << 16; return v.f;
}

// ---------------------------------------------------------------------------
// Pack: Wt bf16 [NREAL][S] (= W^T of [sel_w1 | v_w1]) and key_wT [H][E][U]
// ---------------------------------------------------------------------------
__global__ __launch_bounds__(256) void pack_w_kernel(
        const float* __restrict__ sel_w1, const float* __restrict__ v_w1,
        const float* __restrict__ key_w,
        unsigned short* __restrict__ Wt, float* __restrict__ kwT) {
    int idx = blockIdx.x * 256 + threadIdx.x;
    if (idx < NREAL * S_N) {
        int n = idx >> 11;          // / 2048
        int k = idx & 2047;
        float val;
        if (n < 256) {
            int h = n >> 6, kk = n & 63;
            val = sel_w1[((size_t)h * S_N + k) * HYP_N + kk];
        } else {
            val = v_w1[(size_t)k * E_N + (n - 256)];
        }
        Wt[idx] = f2b(val);
    } else if (idx < NREAL * S_N + H_N * E_N * U_N) {
        int j = idx - NREAL * S_N;          // [h][e][u]
        int h = j >> 11, e = (j >> 6) & 31, u = j & 63;
        kwT[j] = key_w[((size_t)h * U_N + u) * E_N + e];
    }
}

// ---------------------------------------------------------------------------
// MFMA GEMM v2: C1[B][288] = relu_bf16(states @ W + bias)
// BM=64 BN=288(all) BK=64 -> grid = 256 blocks, A (fp32) read ONCE from HBM,
// converted to bf16 in-register during LDS staging. B via global_load_lds
// width=16 with XOR-swizzled source chunks. 4 waves: 2-way M x 2-way N split.
// ---------------------------------------------------------------------------
#define GM_BM 64
#define GM_BK 64

__global__ __launch_bounds__(256) void gemm2_kernel(
        const float* __restrict__ states, const unsigned short* __restrict__ Wt,
        const float* __restrict__ sel_b1, const float* __restrict__ v_b1,
        unsigned short* __restrict__ C1) {
    __shared__ __align__(16) unsigned short Asm[GM_BM * GM_BK];   //  8 KB [r][k]
    __shared__ __align__(16) unsigned short Bsm[NREAL * GM_BK];   // 36 KB [n][k]

    const int t = threadIdx.x;
    const int lane = t & 63;
    const int w = t >> 6;
    const int m0 = blockIdx.x * GM_BM;
    const int mw = (w >> 1) * 32;      // 2-way M split: 32 rows per wave
    const int nw = (w & 1) * 144;      // 2-way N split: 144 cols (9 tiles)

    floatx4_t acc[2][9] = {};

    for (int k0 = 0; k0 < S_N; k0 += GM_BK) {
        __syncthreads();   // previous tile's LDS reads done before overwrite

        // A: load fp32 (once from HBM), cvt->bf16, swizzled ds_write_b128.
        // 512 chunks of 8 elems; 2 per thread.
        float4 av[2][2];
#pragma unroll
        for (int i = 0; i < 2; ++i) {
            int p = i * 256 + t, r = p >> 3, cl = p & 7;
            const float* g = states + (size_t)(m0 + r) * S_N + k0 + cl * 8;
            av[i][0] = *(const float4*)g;
            av[i][1] = *(const float4*)(g + 4);
        }
        // B: 2304 chunks of 16 B; 9 per thread, async into LDS.
#pragma unroll
        for (int i = 0; i < 9; ++i) {
            int p = i * 256 + t, n = p >> 3, sl = p & 7;
            int cl = sl ^ (n & 7);
            const unsigned short* g = Wt + (size_t)n * S_N + k0 + cl * 8;
            __builtin_amdgcn_global_load_lds(AS1(g), AS3(Bsm + p * 8), 16, 0, 0);
        }
#pragma unroll
        for (int i = 0; i < 2; ++i) {
            int p = i * 256 + t, r = p >> 3, cl = p & 7;
            int ph = cl ^ (r & 7);
            uint4 o;
            o.x = (unsigned)f2b(av[i][0].x) | ((unsigned)f2b(av[i][0].y) << 16);
            o.y = (unsigned)f2b(av[i][0].z) | ((unsigned)f2b(av[i][0].w) << 16);
            o.z = (unsigned)f2b(av[i][1].x) | ((unsigned)f2b(av[i][1].y) << 16);
            o.w = (unsigned)f2b(av[i][1].z) | ((unsigned)f2b(av[i][1].w) << 16);
            *(uint4*)(Asm + (size_t)(r * 8 + ph) * 8) = o;
        }
        __syncthreads();   // drain ds_writes + global_load_lds

#pragma unroll
        for (int s = 0; s < 2; ++s) {       // two K=32 steps
            const int c = s * 4 + (lane >> 4);
            bf16x8_t afr[2];
#pragma unroll
            for (int mt = 0; mt < 2; ++mt) {
                int r = mw + mt * 16 + (lane & 15);
                int ph = c ^ (r & 7);
                afr[mt] = *(const bf16x8_t*)(Asm + r * 64 + ph * 8);
            }
#pragma unroll
            for (int nt = 0; nt < 9; ++nt) {
                int n = nw + nt * 16 + (lane & 15);
                int ph = c ^ (n & 7);
                bf16x8_t bfr = *(const bf16x8_t*)(Bsm + n * 64 + ph * 8);
                acc[0][nt] = __builtin_amdgcn_mfma_f32_16x16x32_bf16(
                    afr[0], bfr, acc[0][nt], 0, 0, 0);
                acc[1][nt] = __builtin_amdgcn_mfma_f32_16x16x32_bf16(
                    afr[1], bfr, acc[1][nt], 0, 0, 0);
            }
        }
    }

    // bias + relu, store bf16. C/D layout: col=lane&15, row=(lane>>4)*4+reg
#pragma unroll
    for (int nt = 0; nt < 9; ++nt) {
        int n = nw + nt * 16 + (lane & 15);
        float bias = (n < 256) ? sel_b1[n] : v_b1[n - 256];
#pragma unroll
        for (int mt = 0; mt < 2; ++mt) {
            int rbase = m0 + mw + mt * 16 + (lane >> 4) * 4;
#pragma unroll
            for (int rg = 0; rg < 4; ++rg) {
                float v = acc[mt][nt][rg] + bias;
                C1[(size_t)(rbase + rg) * NREAL + n] = f2b(v > 0.0f ? v : 0.0f);
            }
        }
    }
}

// ---------------------------------------------------------------------------
// Epilogue: 256 thr = 4 waves, one wave per batch row. states read as fp32
// (L3-resident after gemm2's streaming pass).
// ---------------------------------------------------------------------------
__global__ __launch_bounds__(256) void epilogue2_kernel(
        const float* __restrict__ states, const unsigned short* __restrict__ C1,
        const float* __restrict__ sel_w2, const float* __restrict__ kwT,
        const float* __restrict__ v_w2, const float* __restrict__ v_b2,
        float* __restrict__ out, float* __restrict__ pmag, float* __restrict__ pent) {
    __shared__ float us[4][A_N * 65];    // stride 65: logits phase conflict-free
    __shared__ float h1s[4][NREAL];
    __shared__ float sel_s[4][H_N * E_N];
    __shared__ float ts[4][H_N * U_N];

    const int t = threadIdx.x;
    const int w = t >> 6;
    const int lane = t & 63;
    const int b = blockIdx.x * 4 + w;

    // stage states row (fp32, coalesced float4)
    {
        const float4* src = (const float4*)(states + (size_t)b * S_N);
#pragma unroll
        for (int i = 0; i < 8; ++i) {
            int f = i * 64 + lane;                  // float4 index 0..511
            float4 v4 = src[f];
            int a = f >> 4, u = (f & 15) << 2;
            float* d = &us[w][a * 65 + u];
            d[0] = v4.x; d[1] = v4.y; d[2] = v4.z; d[3] = v4.w;
        }
    }
    // stage h1 row (288 bf16 = 36 16B-chunks)
    if (lane < 36) {
        uint4 v = *(const uint4*)(C1 + (size_t)b * NREAL + lane * 8);
        float* d = &h1s[w][lane * 8];
        d[0] = b2f(v.x & 0xffff); d[1] = b2f(v.x >> 16);
        d[2] = b2f(v.y & 0xffff); d[3] = b2f(v.y >> 16);
        d[4] = b2f(v.z & 0xffff); d[5] = b2f(v.z >> 16);
        d[6] = b2f(v.w & 0xffff); d[7] = b2f(v.w >> 16);
    }
    __syncthreads();

    // selectors[h][e]
#pragma unroll
    for (int l = 0; l < 2; ++l) {
        int idx = l * 64 + lane, h = idx >> 5, e = idx & 31;
        const float* hh = &h1s[w][h * HYP_N];
        const float* w2 = sel_w2 + (size_t)h * HYP_N * E_N + e;
        float s = 0.0f;
#pragma unroll
        for (int k = 0; k < HYP_N; ++k) s = fmaf(hh[k], w2[(size_t)k * E_N], s);
        sel_s[w][idx] = s;
    }
    __syncthreads();

    // t[h][u] via key_wT (coalesced over u)
#pragma unroll
    for (int l = 0; l < 4; ++l) {
        int idx = l * 64 + lane, h = idx >> 6, u = idx & 63;
        const float* sh = &sel_s[w][h * E_N];
        const float* kw = kwT + (size_t)h * E_N * U_N + u;
        float s = 0.0f;
#pragma unroll
        for (int e = 0; e < E_N; ++e) s = fmaf(sh[e], kw[(size_t)e * U_N], s);
        ts[w][idx] = s;
    }
    __syncthreads();

    // logits + softmax (32-lane segments align with (h,a) groups)
    float wgt[2];
    float mag = 0.0f;
#pragma unroll
    for (int l = 0; l < 2; ++l) {
        int idx = l * 64 + lane, h = idx >> 5, a = idx & 31;
        const float* ua = &us[w][a * 65];
        const float* th = &ts[w][h * U_N];
        float lg = 0.0f;
#pragma unroll
        for (int u = 0; u < U_N; ++u) lg = fmaf(ua[u], th[u], lg);
        mag += lg * lg;

        float x = lg * 0.17677669529663687f;  // 1/sqrt(32)
        float m = x;
#pragma unroll
        for (int o = 16; o > 0; o >>= 1) m = fmaxf(m, __shfl_xor(m, o, 32));
        float p = expf(x - m);
        float den = p;
#pragma unroll
        for (int o = 16; o > 0; o >>= 1) den += __shfl_xor(den, o, 32);
        float wv = p / den;
        wgt[l] = wv;

        float ent = wv * logf(wv + 1e-8f);
#pragma unroll
        for (int o = 16; o > 0; o >>= 1) ent += __shfl_xor(ent, o, 32);
        if (a == 0) pent[(size_t)h * B_N + b] = ent;
    }

    // mag: 64-lane reduce covers all 128 logits of the row
#pragma unroll
    for (int o = 32; o > 0; o >>= 1) mag += __shfl_xor(mag, o, 64);
    if (lane == 0) pmag[b] = mag;

    // head_attend: lane holds (h, h+2); partner lane^32 holds (h^1, (h^1)+2)
    float partial = wgt[0] + wgt[1];
    partial += __shfl_xor(partial, 32, 64);
    if (lane < 32) out[(size_t)b * A_N + lane] = partial;

    // v head
    if (lane < 32) {
        float p = h1s[w][256 + lane] * v_w2[lane];
#pragma unroll
        for (int o = 16; o > 0; o >>= 1) p += __shfl_xor(p, o, 32);
        if (lane == 0) out[OUT_V + b] = p + v_b2[0];
    }
}

// ---------------------------------------------------------------------------
// Deterministic final reduction
// ---------------------------------------------------------------------------
__global__ __launch_bounds__(256) void finalize_kernel(
        const float* __restrict__ pmag, const float* __restrict__ pent,
        float* __restrict__ out) {
    int which = blockIdx.x;   // 0..4
    const float* src = (which == 0) ? pmag : (pent + (size_t)(which - 1) * B_N);
    float s = 0.0f;
    for (int i = threadIdx.x; i < B_N; i += 256) s += src[i];
#pragma unroll
    for (int o = 32; o > 0; o >>= 1) s += __shfl_xor(s, o, 64);
    __shared__ float red[4];
    if ((threadIdx.x & 63) == 0) red[threadIdx.x >> 6] = s;
    __syncthreads();
    if (threadIdx.x == 0) {
        float tot = red[0] + red[1] + red[2] + red[3];
        if (which == 0) out[OUT_MAG] = 1e-3f * tot / (float)(B_N * A_N);
        else out[OUT_ENT + which - 1] = -tot / (float)B_N;
    }
}

// ---------------------------------------------------------------------------
extern "C" void kernel_launch(void* const* d_in, const int* in_sizes, int n_in,
                              void* d_out, int out_size, void* d_ws, size_t ws_size,
                              hipStream_t stream) {
    const float* states = (const float*)d_in[1];
    const float* sel_w1 = (const float*)d_in[2];
    const float* sel_b1 = (const float*)d_in[3];
    const float* sel_w2 = (const float*)d_in[4];
    const float* key_w  = (const float*)d_in[5];
    const float* v_w1   = (const float*)d_in[6];
    const float* v_b1   = (const float*)d_in[7];
    const float* v_w2   = (const float*)d_in[8];
    const float* v_b2   = (const float*)d_in[9];
    float* out = (float*)d_out;
    char* wsb  = (char*)d_ws;

    unsigned short* Wt  = (unsigned short*)(wsb + WS_WT);
    unsigned short* C1  = (unsigned short*)(wsb + WS_C1);
    float* kwT          = (float*)(wsb + WS_KWT);
    float* pmag         = (float*)(wsb + WS_PMAG);
    float* pent         = (float*)(wsb + WS_PENT);

    pack_w_kernel<<<dim3((NREAL * S_N + H_N * E_N * U_N + 255) / 256), dim3(256), 0, stream>>>(
        sel_w1, v_w1, key_w, Wt, kwT);
    gemm2_kernel<<<dim3(B_N / GM_BM), dim3(256), 0, stream>>>(
        states, Wt, sel_b1, v_b1, C1);
    epilogue2_kernel<<<dim3(B_N / 4), dim3(256), 0, stream>>>(
        states, C1, sel_w2, kwT, v_w2, v_b2, out, pmag, pent);
    finalize_kernel<<<dim3(5), dim3(256), 0, stream>>>(pmag, pent, out);
}

// Round 4
// 295.725 us; speedup vs baseline: 1.8746x; 1.0783x over previous
//
#include <hip/hip_runtime.h>
#include <hip/hip_bf16.h>

// Problem constants
#define B_N 16384
#define A_N 32
#define U_N 64
#define S_N 2048
#define E_N 32
#define HYP_N 64
#define H_N 4
#define NREAL 288   // 256 selector-hypernet cols + 32 v-net cols
#define NPADG 320   // GEMM N padded to 320 (20 MFMA col-tiles)

// workspace byte offsets (16B-aligned)
#define WS_WT    0                         // Wt bf16 [320][2048] = 1310720 B
#define WS_C1    1310720                   // C1 bf16 [B][288]    = 9437184 B
#define WS_MB    (WS_C1 + 9437184)         // Mb bf16 [H][U][K=64] = 32768 B
#define WS_PMAG  (WS_MB + 32768)
#define WS_PENT  (WS_PMAG + 65536)
// total ~11.1 MB

// output layout (floats): head_attend [B,A] | v [B] | mag | ent [H]
#define OUT_V   (B_N * A_N)
#define OUT_MAG (OUT_V + B_N)
#define OUT_ENT (OUT_MAG + 1)

typedef __attribute__((ext_vector_type(8))) short bf16x8_t;
typedef __attribute__((ext_vector_type(4))) float floatx4_t;

#define AS1(p) ((const __attribute__((address_space(1))) void*)(p))
#define AS3(p) ((__attribute__((address_space(3))) void*)(p))

__device__ __forceinline__ unsigned short f2b(float f) {
    union { float f; unsigned u; } v; v.f = f;
    unsigned r = v.u + 0x7FFFu + ((v.u >> 16) & 1u);   // RNE
    return (unsigned short)(r >> 16);
}
__device__ __forceinline__ float b2f(unsigned x) {
    union { unsigned u; float f; } v; v.u = x << 16; return v.f;
}

// ---------------------------------------------------------------------------
// Pack: Wt bf16 [320][2048] (W^T of [sel_w1 | v_w1 | 0]) and
//       Mb bf16 [H][U][64]: M[h][u][k] = sum_e key_w[h][u][e]*sel_w2[h][k][e]
// (t[h][u] = sum_k h1[h][k] * M[h][u][k] — selector stage folded away)
// ---------------------------------------------------------------------------
__global__ __launch_bounds__(256) void pack_w_kernel(
        const float* __restrict__ sel_w1, const float* __restrict__ v_w1,
        const float* __restrict__ sel_w2, const float* __restrict__ key_w,
        unsigned short* __restrict__ Wt, unsigned short* __restrict__ Mb) {
    int idx = blockIdx.x * 256 + threadIdx.x;
    if (idx < NPADG * S_N) {
        int n = idx >> 11;          // / 2048
        int k = idx & 2047;
        float val = 0.0f;
        if (n < 256) {
            int h = n >> 6, kk = n & 63;
            val = sel_w1[((size_t)h * S_N + k) * HYP_N + kk];
        } else if (n < NREAL) {
            val = v_w1[(size_t)k * E_N + (n - 256)];
        }
        Wt[idx] = f2b(val);
    } else if (idx < NPADG * S_N + H_N * U_N * HYP_N) {
        int j = idx - NPADG * S_N;          // [h][u][k]
        int h = j >> 12, u = (j >> 6) & 63, k = j & 63;
        const float* kw = key_w + ((size_t)h * U_N + u) * E_N;
        const float* w2 = sel_w2 + ((size_t)h * HYP_N + k) * E_N;
        float s = 0.0f;
#pragma unroll
        for (int e = 0; e < E_N; ++e) s = fmaf(kw[e], w2[e], s);
        Mb[j] = f2b(s);
    }
}

// ---------------------------------------------------------------------------
// MFMA GEMM v3: C1[B][288] = relu_bf16(states @ W + bias)
// BM=64 BN=320 BK=64, 512 thr (8 waves: 2-way M x 4-way N), grid 256.
// 2-barrier pipeline: A fp32 prefetched into regs one iter ahead (converted
// bf16 at ds_write); B via global_load_lds w=16 (L2-hot). XOR-swizzled LDS.
// ---------------------------------------------------------------------------
#define GM_BM 64
#define GM_BK 64

__global__ __launch_bounds__(512) void gemm3_kernel(
        const float* __restrict__ states, const unsigned short* __restrict__ Wt,
        const float* __restrict__ sel_b1, const float* __restrict__ v_b1,
        unsigned short* __restrict__ C1) {
    __shared__ __align__(16) unsigned short Asm[GM_BM * GM_BK];    //  8 KB [r][k]
    __shared__ __align__(16) unsigned short Bsm[NPADG * GM_BK];    // 40 KB [n][k]

    const int t = threadIdx.x;
    const int lane = t & 63;
    const int w = t >> 6;               // 0..7
    const int m0 = blockIdx.x * GM_BM;
    const int mw = (w & 1) * 32;        // 2-way M: 32 rows/wave
    const int nw = (w >> 1) * 80;       // 4-way N: 80 cols (5 tiles)/wave

    const int ar = t >> 3, acl = t & 7;             // A chunk: row, k-oct
    const float* ap = states + (size_t)(m0 + ar) * S_N + acl * 8;

    floatx4_t acc[2][5] = {};

    // prologue: A(0) regs -> LDS, issue B(0)
    float4 a0 = *(const float4*)(ap);
    float4 a1 = *(const float4*)(ap + 4);
    {
        int ph = acl ^ (ar & 7);
        uint4 o;
        o.x = (unsigned)f2b(a0.x) | ((unsigned)f2b(a0.y) << 16);
        o.y = (unsigned)f2b(a0.z) | ((unsigned)f2b(a0.w) << 16);
        o.z = (unsigned)f2b(a1.x) | ((unsigned)f2b(a1.y) << 16);
        o.w = (unsigned)f2b(a1.z) | ((unsigned)f2b(a1.w) << 16);
        *(uint4*)(Asm + (size_t)(ar * 8 + ph) * 8) = o;
    }
#pragma unroll
    for (int i = 0; i < 5; ++i) {
        int p = i * 512 + t, n = p >> 3, sl = p & 7;
        int cl = sl ^ (n & 7);
        __builtin_amdgcn_global_load_lds(AS1(Wt + (size_t)n * S_N + cl * 8),
                                         AS3(Bsm + p * 8), 16, 0, 0);
    }
    __syncthreads();

    for (int it = 0; it < 32; ++it) {
        // prefetch A(it+1) into regs — lands during MFMA phase
        if (it < 31) {
            const float* g = ap + (it + 1) * GM_BK;
            a0 = *(const float4*)(g);
            a1 = *(const float4*)(g + 4);
        }
        // MFMA on LDS tile `it`
#pragma unroll
        for (int s = 0; s < 2; ++s) {
            const int c = s * 4 + (lane >> 4);
            bf16x8_t afr[2];
#pragma unroll
            for (int mt = 0; mt < 2; ++mt) {
                int r = mw + mt * 16 + (lane & 15);
                int ph = c ^ (r & 7);
                afr[mt] = *(const bf16x8_t*)(Asm + r * 64 + ph * 8);
            }
#pragma unroll
            for (int nt = 0; nt < 5; ++nt) {
                int n = nw + nt * 16 + (lane & 15);
                int ph = c ^ (n & 7);
                bf16x8_t bfr = *(const bf16x8_t*)(Bsm + n * 64 + ph * 8);
                acc[0][nt] = __builtin_amdgcn_mfma_f32_16x16x32_bf16(
                    afr[0], bfr, acc[0][nt], 0, 0, 0);
                acc[1][nt] = __builtin_amdgcn_mfma_f32_16x16x32_bf16(
                    afr[1], bfr, acc[1][nt], 0, 0, 0);
            }
        }
        __syncthreads();   // readers done (also drains A prefetch)
        if (it < 31) {
            int k0 = (it + 1) * GM_BK;
            {
                int ph = acl ^ (ar & 7);
                uint4 o;
                o.x = (unsigned)f2b(a0.x) | ((unsigned)f2b(a0.y) << 16);
                o.y = (unsigned)f2b(a0.z) | ((unsigned)f2b(a0.w) << 16);
                o.z = (unsigned)f2b(a1.x) | ((unsigned)f2b(a1.y) << 16);
                o.w = (unsigned)f2b(a1.z) | ((unsigned)f2b(a1.w) << 16);
                *(uint4*)(Asm + (size_t)(ar * 8 + ph) * 8) = o;
            }
#pragma unroll
            for (int i = 0; i < 5; ++i) {
                int p = i * 512 + t, n = p >> 3, sl = p & 7;
                int cl = sl ^ (n & 7);
                __builtin_amdgcn_global_load_lds(
                    AS1(Wt + (size_t)n * S_N + k0 + cl * 8),
                    AS3(Bsm + p * 8), 16, 0, 0);
            }
            __syncthreads();   // staging visible before next MFMA phase
        }
    }

    // bias + relu, store bf16. C/D layout: col=lane&15, row=(lane>>4)*4+reg
#pragma unroll
    for (int nt = 0; nt < 5; ++nt) {
        int n = nw + nt * 16 + (lane & 15);
        if (n >= NREAL) continue;
        float bias = (n < 256) ? sel_b1[n] : v_b1[n - 256];
#pragma unroll
        for (int mt = 0; mt < 2; ++mt) {
            int rbase = m0 + mw + mt * 16 + (lane >> 4) * 4;
#pragma unroll
            for (int rg = 0; rg < 4; ++rg) {
                float v = acc[mt][nt][rg] + bias;
                C1[(size_t)(rbase + rg) * NREAL + n] = f2b(v > 0.0f ? v : 0.0f);
            }
        }
    }
}

// ---------------------------------------------------------------------------
// Epilogue v3: 32 rows/block, 256 thr (4 waves), grid 512.
// Phase T: per-wave MFMA t[r][h][u] = sum_k h1[r][h][k]*M[h][u][k] (wave=head).
// Phase L: per-wave 8 rows; lane=(a, u-half); us fp32 from global (L3-hot);
// halves combined via shfl_xor(32); softmax/mag/ent/v in shuffles.
// ---------------------------------------------------------------------------
#define EP_ROWS 32
#define H1_STRIDE 312   // shorts; /8=39 odd -> A-frag reads 2-way-bank max
#define TS_STRIDE 260

__global__ __launch_bounds__(256) void epilogue3_kernel(
        const float* __restrict__ states, const unsigned short* __restrict__ C1,
        const unsigned short* __restrict__ Mb,
        const float* __restrict__ v_w2, const float* __restrict__ v_b2,
        float* __restrict__ out, float* __restrict__ pmag, float* __restrict__ pent) {
    __shared__ __align__(16) unsigned short h1s[EP_ROWS][H1_STRIDE]; // 19.97 KB bf16
    __shared__ float ts[EP_ROWS][TS_STRIDE];                          // 33.3 KB fp32

    const int t = threadIdx.x;
    const int w = t >> 6;
    const int lane = t & 63;
    const int b0 = blockIdx.x * EP_ROWS;

    // ---- stage h1 (bf16, 32 rows x 36 16B-chunks = 1152 chunks) ----
    // layout per row: h-slot h*72 holds k=0..63 (+8 pad); v[j] packed into
    // pads at (j>>3)*72+64+(j&7)
#pragma unroll
    for (int i = 0; i < 5; ++i) {
        int c = i * 256 + t;
        if (c < EP_ROWS * 36) {
            int r = c / 36, cc = c - r * 36;
            int n = cc * 8;
            uint4 v = *(const uint4*)(C1 + (size_t)(b0 + r) * NREAL + n);
            int idx = (n < 256) ? ((n >> 6) * 72 + (n & 63))
                                : (((n - 256) >> 3) * 72 + 64);
            *(uint4*)&h1s[r][idx] = v;
        }
    }
    __syncthreads();

    // ---- phase T: wave w computes head h=w for all 32 rows via MFMA ----
    {
        const int h = w;
        floatx4_t tacc[2][4] = {};
#pragma unroll
        for (int s = 0; s < 2; ++s) {
            int k0 = s * 32 + (lane >> 4) * 8;
            bf16x8_t bfr[4];
#pragma unroll
            for (int ut = 0; ut < 4; ++ut) {
                int u = ut * 16 + (lane & 15);
                bfr[ut] = *(const bf16x8_t*)(Mb + ((size_t)(h * U_N + u) * 64) + k0);
            }
#pragma unroll
            for (int mt = 0; mt < 2; ++mt) {
                int r = mt * 16 + (lane & 15);
                bf16x8_t afr = *(const bf16x8_t*)&h1s[r][h * 72 + k0];
#pragma unroll
                for (int ut = 0; ut < 4; ++ut)
                    tacc[mt][ut] = __builtin_amdgcn_mfma_f32_16x16x32_bf16(
                        afr, bfr[ut], tacc[mt][ut], 0, 0, 0);
            }
        }
        // D layout: col=lane&15 (u), row=(lane>>4)*4+rg (r)
#pragma unroll
        for (int mt = 0; mt < 2; ++mt)
#pragma unroll
            for (int ut = 0; ut < 4; ++ut)
#pragma unroll
                for (int rg = 0; rg < 4; ++rg) {
                    int r = mt * 16 + (lane >> 4) * 4 + rg;
                    int u = ut * 16 + (lane & 15);
                    ts[r][h * U_N + u] = tacc[mt][ut][rg];
                }
    }
    __syncthreads();

    // ---- phase L: wave w handles rows w*8 .. w*8+7 ----
    const int a = lane & 31, uh = lane >> 5;
    float4 cur[8], nxt[8];
    {
        const float* up = states + (size_t)(b0 + w * 8) * S_N + a * 64 + uh * 32;
#pragma unroll
        for (int i = 0; i < 8; ++i) cur[i] = ((const float4*)up)[i];
    }
    for (int rr = 0; rr < 8; ++rr) {
        int r = w * 8 + rr;
        int b = b0 + r;
        if (rr < 7) {
            const float* up = states + (size_t)(b + 1) * S_N + a * 64 + uh * 32;
#pragma unroll
            for (int i = 0; i < 8; ++i) nxt[i] = ((const float4*)up)[i];
        }
        float pl[4];
#pragma unroll
        for (int h = 0; h < 4; ++h) {
            const float* tp = &ts[r][h * U_N + uh * 32];
            float s = 0.0f;
#pragma unroll
            for (int i = 0; i < 8; ++i) {
                float4 t4 = *(const float4*)(tp + i * 4);
                s = fmaf(cur[i].x, t4.x, s);
                s = fmaf(cur[i].y, t4.y, s);
                s = fmaf(cur[i].z, t4.z, s);
                s = fmaf(cur[i].w, t4.w, s);
            }
            pl[h] = s + __shfl_xor(s, 32, 64);   // combine u-halves
        }
        // mag
        float mg = pl[0]*pl[0] + pl[1]*pl[1] + pl[2]*pl[2] + pl[3]*pl[3];
#pragma unroll
        for (int o = 16; o > 0; o >>= 1) mg += __shfl_xor(mg, o, 32);
        // softmax + entropy per head, head_attend accumulation
        float hatt = 0.0f;
        float entv[4];
#pragma unroll
        for (int h = 0; h < 4; ++h) {
            float x = pl[h] * 0.17677669529663687f;   // 1/sqrt(E=32)
            float m = x;
#pragma unroll
            for (int o = 16; o > 0; o >>= 1) m = fmaxf(m, __shfl_xor(m, o, 32));
            float p = expf(x - m);
            float den = p;
#pragma unroll
            for (int o = 16; o > 0; o >>= 1) den += __shfl_xor(den, o, 32);
            float wv = p / den;
            hatt += wv;
            float e = wv * logf(wv + 1e-8f);
#pragma unroll
            for (int o = 16; o > 0; o >>= 1) e += __shfl_xor(e, o, 32);
            entv[h] = e;
        }
        if (uh == 0) {
            out[(size_t)b * A_N + a] = hatt;
            // v head: bf16 h1 v-slot
            float pv = b2f((unsigned)h1s[r][(a >> 3) * 72 + 64 + (a & 7)]) * v_w2[a];
#pragma unroll
            for (int o = 16; o > 0; o >>= 1) pv += __shfl_xor(pv, o, 32);
            if (a == 0) {
                out[OUT_V + b] = pv + v_b2[0];
                pmag[b] = mg;
#pragma unroll
                for (int h = 0; h < 4; ++h) pent[(size_t)h * B_N + b] = entv[h];
            }
        }
#pragma unroll
        for (int i = 0; i < 8; ++i) cur[i] = nxt[i];
    }
}

// ---------------------------------------------------------------------------
// Deterministic final reduction
// ---------------------------------------------------------------------------
__global__ __launch_bounds__(256) void finalize_kernel(
        const float* __restrict__ pmag, const float* __restrict__ pent,
        float* __restrict__ out) {
    int which = blockIdx.x;   // 0..4
    const float* src = (which == 0) ? pmag : (pent + (size_t)(which - 1) * B_N);
    float s = 0.0f;
    for (int i = threadIdx.x; i < B_N; i += 256) s += src[i];
#pragma unroll
    for (int o = 32; o > 0; o >>= 1) s += __shfl_xor(s, o, 64);
    __shared__ float red[4];
    if ((threadIdx.x & 63) == 0) red[threadIdx.x >> 6] = s;
    __syncthreads();
    if (threadIdx.x == 0) {
        float tot = red[0] + red[1] + red[2] + red[3];
        if (which == 0) out[OUT_MAG] = 1e-3f * tot / (float)(B_N * A_N);
        else out[OUT_ENT + which - 1] = -tot / (float)B_N;
    }
}

// ---------------------------------------------------------------------------
extern "C" void kernel_launch(void* const* d_in, const int* in_sizes, int n_in,
                              void* d_out, int out_size, void* d_ws, size_t ws_size,
                              hipStream_t stream) {
    const float* states = (const float*)d_in[1];
    const float* sel_w1 = (const float*)d_in[2];
    const float* sel_b1 = (const float*)d_in[3];
    const float* sel_w2 = (const float*)d_in[4];
    const float* key_w  = (const float*)d_in[5];
    const float* v_w1   = (const float*)d_in[6];
    const float* v_b1   = (const float*)d_in[7];
    const float* v_w2   = (const float*)d_in[8];
    const float* v_b2   = (const float*)d_in[9];
    float* out = (float*)d_out;
    char* wsb  = (char*)d_ws;

    unsigned short* Wt  = (unsigned short*)(wsb + WS_WT);
    unsigned short* C1  = (unsigned short*)(wsb + WS_C1);
    unsigned short* Mb  = (unsigned short*)(wsb + WS_MB);
    float* pmag         = (float*)(wsb + WS_PMAG);
    float* pent         = (float*)(wsb + WS_PENT);

    pack_w_kernel<<<dim3((NPADG * S_N + H_N * U_N * HYP_N + 255) / 256),
                    dim3(256), 0, stream>>>(sel_w1, v_w1, sel_w2, key_w, Wt, Mb);
    gemm3_kernel<<<dim3(B_N / GM_BM), dim3(512), 0, stream>>>(
        states, Wt, sel_b1, v_b1, C1);
    epilogue3_kernel<<<dim3(B_N / EP_ROWS), dim3(256), 0, stream>>>(
        states, C1, Mb, v_w2, v_b2, out, pmag, pent);
    finalize_kernel<<<dim3(5), dim3(256), 0, stream>>>(pmag, pent, out);
}

// Round 5
// 286.155 us; speedup vs baseline: 1.9373x; 1.0334x over previous
//
#include <hip/hip_runtime.h>
#include <hip/hip_bf16.h>

// Problem constants
#define B_N 16384
#define A_N 32
#define U_N 64
#define S_N 2048
#define E_N 32
#define HYP_N 64
#define H_N 4
#define NREAL 288   // 256 selector-hypernet cols + 32 v-net cols
#define NPADG 320   // GEMM N padded to 320 (20 MFMA col-tiles)

// workspace byte offsets (16B-aligned)
#define WS_WT    0                         // Wt bf16 [320][2048] = 1310720 B
#define WS_MB    1310720                   // Mb bf16 [H][U][64]  = 32768 B
#define WS_PMAG  (WS_MB + 32768)
#define WS_PENT  (WS_PMAG + 65536)

// output layout (floats): head_attend [B,A] | v [B] | mag | ent [H]
#define OUT_V   (B_N * A_N)
#define OUT_MAG (OUT_V + B_N)
#define OUT_ENT (OUT_MAG + 1)

typedef __attribute__((ext_vector_type(8))) short bf16x8_t;
typedef __attribute__((ext_vector_type(4))) float floatx4_t;

#define AS1(p) ((const __attribute__((address_space(1))) void*)(p))
#define AS3(p) ((__attribute__((address_space(3))) void*)(p))

__device__ __forceinline__ unsigned short f2b(float f) {
    union { float f; unsigned u; } v; v.f = f;
    unsigned r = v.u + 0x7FFFu + ((v.u >> 16) & 1u);   // RNE
    return (unsigned short)(r >> 16);
}
__device__ __forceinline__ float b2f(unsigned x) {
    union { unsigned u; float f; } v; v.u = x << 16; return v.f;
}

// ---------------------------------------------------------------------------
// Pack: Wt bf16 [320][2048] (W^T of [sel_w1 | v_w1 | 0]) and
//       Mb bf16 [H][U][64]: M[h][u][k] = sum_e key_w[h][u][e]*sel_w2[h][k][e]
// ---------------------------------------------------------------------------
__global__ __launch_bounds__(256) void pack_w_kernel(
        const float* __restrict__ sel_w1, const float* __restrict__ v_w1,
        const float* __restrict__ sel_w2, const float* __restrict__ key_w,
        unsigned short* __restrict__ Wt, unsigned short* __restrict__ Mb) {
    int idx = blockIdx.x * 256 + threadIdx.x;
    if (idx < NPADG * S_N) {
        int n = idx >> 11;          // / 2048
        int k = idx & 2047;
        float val = 0.0f;
        if (n < 256) {
            int h = n >> 6, kk = n & 63;
            val = sel_w1[((size_t)h * S_N + k) * HYP_N + kk];
        } else if (n < NREAL) {
            val = v_w1[(size_t)k * E_N + (n - 256)];
        }
        Wt[idx] = f2b(val);
    } else if (idx < NPADG * S_N + H_N * U_N * HYP_N) {
        int j = idx - NPADG * S_N;          // [h][u][k]
        int h = j >> 12, u = (j >> 6) & 63, k = j & 63;
        const float* kw = key_w + ((size_t)h * U_N + u) * E_N;
        const float* w2 = sel_w2 + ((size_t)h * HYP_N + k) * E_N;
        float s = 0.0f;
#pragma unroll
        for (int e = 0; e < E_N; ++e) s = fmaf(kw[e], w2[e], s);
        Mb[j] = f2b(s);
    }
}

// ---------------------------------------------------------------------------
// Fused kernel: GEMM (BM=32, BN=320, BK=64) + bias/relu -> h1 in LDS +
// phase T (MFMA t = h1 @ M^T) + phase L (logits/softmax/outputs).
// 256 thr (4 waves), grid 512 -> 2 blocks/CU (two independent barrier
// domains overlap each other's staging drains). A fp32 read ONCE from HBM,
// reg-prefetched one iter ahead; B via global_load_lds w=16, XOR swizzle.
// ts (fp32, phase T output) aliases the Bsm LDS region after the K-loop.
// ---------------------------------------------------------------------------
#define FM_BM 32
#define FM_BK 64
#define H1_STRIDE 312   // shorts
#define TS_STRIDE 260   // floats

__global__ __launch_bounds__(256) void fused_kernel(
        const float* __restrict__ states, const unsigned short* __restrict__ Wt,
        const float* __restrict__ sel_b1, const float* __restrict__ v_b1,
        const unsigned short* __restrict__ Mb,
        const float* __restrict__ v_w2, const float* __restrict__ v_b2,
        float* __restrict__ out, float* __restrict__ pmag, float* __restrict__ pent) {
    // LDS pool: Asm 4096 | Bsm 40960 (ts 33280 aliases) | h1s 19968  = 65024 B
    __shared__ __align__(16) char pool[4096 + 40960 + H1_STRIDE * FM_BM * 2];
    unsigned short* Asm = (unsigned short*)pool;
    unsigned short* Bsm = (unsigned short*)(pool + 4096);
    float*          tsb = (float*)(pool + 4096);                 // aliases Bsm
    unsigned short* h1b = (unsigned short*)(pool + 4096 + 40960);

    const int t = threadIdx.x;
    const int lane = t & 63;
    const int w = t >> 6;               // 0..3
    const int m0 = blockIdx.x * FM_BM;
    const int nw = w * 80;              // 4-way N: 80 cols (5 tiles)/wave

    const int ar = t >> 3, acl = t & 7;             // A chunk: row 0..31, k-oct
    const float* ap = states + (size_t)(m0 + ar) * S_N + acl * 8;

    floatx4_t acc[2][5] = {};

    // ---- K-loop prologue: A(0) regs -> LDS, issue B(0) ----
    float4 a0 = *(const float4*)(ap);
    float4 a1 = *(const float4*)(ap + 4);
    {
        int ph = acl ^ (ar & 7);
        uint4 o;
        o.x = (unsigned)f2b(a0.x) | ((unsigned)f2b(a0.y) << 16);
        o.y = (unsigned)f2b(a0.z) | ((unsigned)f2b(a0.w) << 16);
        o.z = (unsigned)f2b(a1.x) | ((unsigned)f2b(a1.y) << 16);
        o.w = (unsigned)f2b(a1.z) | ((unsigned)f2b(a1.w) << 16);
        *(uint4*)(Asm + (size_t)(ar * 8 + ph) * 8) = o;
    }
#pragma unroll
    for (int i = 0; i < 10; ++i) {
        int p = i * 256 + t, n = p >> 3, sl = p & 7;
        int cl = sl ^ (n & 7);
        __builtin_amdgcn_global_load_lds(AS1(Wt + (size_t)n * S_N + cl * 8),
                                         AS3(Bsm + p * 8), 16, 0, 0);
    }
    __syncthreads();

    for (int it = 0; it < 32; ++it) {
        if (it < 31) {                      // prefetch A(it+1) into regs
            const float* g = ap + (it + 1) * FM_BK;
            a0 = *(const float4*)(g);
            a1 = *(const float4*)(g + 4);
        }
#pragma unroll
        for (int s = 0; s < 2; ++s) {       // two K=32 steps
            const int c = s * 4 + (lane >> 4);
            bf16x8_t afr[2];
#pragma unroll
            for (int mt = 0; mt < 2; ++mt) {
                int r = mt * 16 + (lane & 15);
                int ph = c ^ (r & 7);
                afr[mt] = *(const bf16x8_t*)(Asm + r * 64 + ph * 8);
            }
#pragma unroll
            for (int nt = 0; nt < 5; ++nt) {
                int n = nw + nt * 16 + (lane & 15);
                int ph = c ^ (n & 7);
                bf16x8_t bfr = *(const bf16x8_t*)(Bsm + n * 64 + ph * 8);
                acc[0][nt] = __builtin_amdgcn_mfma_f32_16x16x32_bf16(
                    afr[0], bfr, acc[0][nt], 0, 0, 0);
                acc[1][nt] = __builtin_amdgcn_mfma_f32_16x16x32_bf16(
                    afr[1], bfr, acc[1][nt], 0, 0, 0);
            }
        }
        __syncthreads();   // LDS readers done; A prefetch drained
        if (it < 31) {
            int k0 = (it + 1) * FM_BK;
            {
                int ph = acl ^ (ar & 7);
                uint4 o;
                o.x = (unsigned)f2b(a0.x) | ((unsigned)f2b(a0.y) << 16);
                o.y = (unsigned)f2b(a0.z) | ((unsigned)f2b(a0.w) << 16);
                o.z = (unsigned)f2b(a1.x) | ((unsigned)f2b(a1.y) << 16);
                o.w = (unsigned)f2b(a1.z) | ((unsigned)f2b(a1.w) << 16);
                *(uint4*)(Asm + (size_t)(ar * 8 + ph) * 8) = o;
            }
#pragma unroll
            for (int i = 0; i < 10; ++i) {
                int p = i * 256 + t, n = p >> 3, sl = p & 7;
                int cl = sl ^ (n & 7);
                __builtin_amdgcn_global_load_lds(
                    AS1(Wt + (size_t)n * S_N + k0 + cl * 8),
                    AS3(Bsm + p * 8), 16, 0, 0);
            }
            __syncthreads();
        }
    }

    // ---- bias + relu -> h1 LDS (bf16). C/D: col=lane&15, row=(lane>>4)*4+rg
    // layout per row: head h at h*72 (k 0..63), v-col j at (j>>3)*72+64+(j&7)
#pragma unroll
    for (int nt = 0; nt < 5; ++nt) {
        int n = nw + nt * 16 + (lane & 15);
        if (n >= NREAL) continue;
        float bias = (n < 256) ? sel_b1[n] : v_b1[n - 256];
        int slot = (n < 256) ? ((n >> 6) * 72 + (n & 63))
                             : (((n - 256) >> 3) * 72 + 64 + ((n - 256) & 7));
#pragma unroll
        for (int mt = 0; mt < 2; ++mt) {
#pragma unroll
            for (int rg = 0; rg < 4; ++rg) {
                int r = mt * 16 + (lane >> 4) * 4 + rg;
                float v = acc[mt][nt][rg] + bias;
                h1b[r * H1_STRIDE + slot] = f2b(v > 0.0f ? v : 0.0f);
            }
        }
    }
    __syncthreads();   // h1 complete; Bsm reads done -> ts may overwrite

    // ---- phase T: wave w = head h; t[r][h][u] via MFMA ----
    {
        const int h = w;
        floatx4_t tacc[2][4] = {};
#pragma unroll
        for (int s = 0; s < 2; ++s) {
            int k0 = s * 32 + (lane >> 4) * 8;
            bf16x8_t bfr[4];
#pragma unroll
            for (int ut = 0; ut < 4; ++ut) {
                int u = ut * 16 + (lane & 15);
                bfr[ut] = *(const bf16x8_t*)(Mb + ((size_t)(h * U_N + u) * 64) + k0);
            }
#pragma unroll
            for (int mt = 0; mt < 2; ++mt) {
                int r = mt * 16 + (lane & 15);
                bf16x8_t afr = *(const bf16x8_t*)(h1b + r * H1_STRIDE + h * 72 + k0);
#pragma unroll
                for (int ut = 0; ut < 4; ++ut)
                    tacc[mt][ut] = __builtin_amdgcn_mfma_f32_16x16x32_bf16(
                        afr, bfr[ut], tacc[mt][ut], 0, 0, 0);
            }
        }
#pragma unroll
        for (int mt = 0; mt < 2; ++mt)
#pragma unroll
            for (int ut = 0; ut < 4; ++ut)
#pragma unroll
                for (int rg = 0; rg < 4; ++rg) {
                    int r = mt * 16 + (lane >> 4) * 4 + rg;
                    int u = ut * 16 + (lane & 15);
                    tsb[r * TS_STRIDE + h * U_N + u] = tacc[mt][ut][rg];
                }
    }
    __syncthreads();

    // ---- phase L: wave w handles rows w*8 .. w*8+7 ----
    const int a = lane & 31, uh = lane >> 5;
    float4 cur[8], nxt[8];
    {
        const float* up = states + (size_t)(m0 + w * 8) * S_N + a * 64 + uh * 32;
#pragma unroll
        for (int i = 0; i < 8; ++i) cur[i] = ((const float4*)up)[i];
    }
    for (int rr = 0; rr < 8; ++rr) {
        int r = w * 8 + rr;
        int b = m0 + r;
        if (rr < 7) {
            const float* up = states + (size_t)(b + 1) * S_N + a * 64 + uh * 32;
#pragma unroll
            for (int i = 0; i < 8; ++i) nxt[i] = ((const float4*)up)[i];
        }
        float pl[4];
#pragma unroll
        for (int h = 0; h < 4; ++h) {
            const float* tp = &tsb[r * TS_STRIDE + h * U_N + uh * 32];
            float s = 0.0f;
#pragma unroll
            for (int i = 0; i < 8; ++i) {
                float4 t4 = *(const float4*)(tp + i * 4);
                s = fmaf(cur[i].x, t4.x, s);
                s = fmaf(cur[i].y, t4.y, s);
                s = fmaf(cur[i].z, t4.z, s);
                s = fmaf(cur[i].w, t4.w, s);
            }
            pl[h] = s + __shfl_xor(s, 32, 64);   // combine u-halves
        }
        float mg = pl[0]*pl[0] + pl[1]*pl[1] + pl[2]*pl[2] + pl[3]*pl[3];
#pragma unroll
        for (int o = 16; o > 0; o >>= 1) mg += __shfl_xor(mg, o, 32);
        float hatt = 0.0f;
        float entv[4];
#pragma unroll
        for (int h = 0; h < 4; ++h) {
            float x = pl[h] * 0.17677669529663687f;   // 1/sqrt(E=32)
            float m = x;
#pragma unroll
            for (int o = 16; o > 0; o >>= 1) m = fmaxf(m, __shfl_xor(m, o, 32));
            float p = expf(x - m);
            float den = p;
#pragma unroll
            for (int o = 16; o > 0; o >>= 1) den += __shfl_xor(den, o, 32);
            float wv = p / den;
            hatt += wv;
            float e = wv * logf(wv + 1e-8f);
#pragma unroll
            for (int o = 16; o > 0; o >>= 1) e += __shfl_xor(e, o, 32);
            entv[h] = e;
        }
        if (uh == 0) {
            out[(size_t)b * A_N + a] = hatt;
            float pv = b2f((unsigned)h1b[r * H1_STRIDE + (a >> 3) * 72 + 64 + (a & 7)])
                       * v_w2[a];
#pragma unroll
            for (int o = 16; o > 0; o >>= 1) pv += __shfl_xor(pv, o, 32);
            if (a == 0) {
                out[OUT_V + b] = pv + v_b2[0];
                pmag[b] = mg;
#pragma unroll
                for (int h = 0; h < 4; ++h) pent[(size_t)h * B_N + b] = entv[h];
            }
        }
#pragma unroll
        for (int i = 0; i < 8; ++i) cur[i] = nxt[i];
    }
}

// ---------------------------------------------------------------------------
// Deterministic final reduction
// ---------------------------------------------------------------------------
__global__ __launch_bounds__(256) void finalize_kernel(
        const float* __restrict__ pmag, const float* __restrict__ pent,
        float* __restrict__ out) {
    int which = blockIdx.x;   // 0..4
    const float* src = (which == 0) ? pmag : (pent + (size_t)(which - 1) * B_N);
    float s = 0.0f;
    for (int i = threadIdx.x; i < B_N; i += 256) s += src[i];
#pragma unroll
    for (int o = 32; o > 0; o >>= 1) s += __shfl_xor(s, o, 64);
    __shared__ float red[4];
    if ((threadIdx.x & 63) == 0) red[threadIdx.x >> 6] = s;
    __syncthreads();
    if (threadIdx.x == 0) {
        float tot = red[0] + red[1] + red[2] + red[3];
        if (which == 0) out[OUT_MAG] = 1e-3f * tot / (float)(B_N * A_N);
        else out[OUT_ENT + which - 1] = -tot / (float)B_N;
    }
}

// ---------------------------------------------------------------------------
extern "C" void kernel_launch(void* const* d_in, const int* in_sizes, int n_in,
                              void* d_out, int out_size, void* d_ws, size_t ws_size,
                              hipStream_t stream) {
    const float* states = (const float*)d_in[1];
    const float* sel_w1 = (const float*)d_in[2];
    const float* sel_b1 = (const float*)d_in[3];
    const float* sel_w2 = (const float*)d_in[4];
    const float* key_w  = (const float*)d_in[5];
    const float* v_w1   = (const float*)d_in[6];
    const float* v_b1   = (const float*)d_in[7];
    const float* v_w2   = (const float*)d_in[8];
    const float* v_b2   = (const float*)d_in[9];
    float* out = (float*)d_out;
    char* wsb  = (char*)d_ws;

    unsigned short* Wt  = (unsigned short*)(wsb + WS_WT);
    unsigned short* Mb  = (unsigned short*)(wsb + WS_MB);
    float* pmag         = (float*)(wsb + WS_PMAG);
    float* pent         = (float*)(wsb + WS_PENT);

    pack_w_kernel<<<dim3((NPADG * S_N + H_N * U_N * HYP_N + 255) / 256),
                    dim3(256), 0, stream>>>(sel_w1, v_w1, sel_w2, key_w, Wt, Mb);
    fused_kernel<<<dim3(B_N / FM_BM), dim3(256), 0, stream>>>(
        states, Wt, sel_b1, v_b1, Mb, v_w2, v_b2, out, pmag, pent);
    finalize_kernel<<<dim3(5), dim3(256), 0, stream>>>(pmag, pent, out);
}